// Round 7
// baseline (231.505 us; speedup 1.0000x reference)
//
#include <hip/hip_runtime.h>
#include <math.h>

// Round 14: fold activation f32->bf16 cast into gemm_qkv A-staging.
//   - gemm_qkv reads query/key/value f32 directly: A-tile reg-staged
//     (issue loads 1 iter early -> latency hidden under MFMA), cvt to bf16
//     in-register, ds_write_b128 to LDS.  Same RTNE cast as prep had ->
//     identical numerics.  B (weights) stays global_load_lds.  Single
//     barrier/iter preserved.
//   - prep shrinks to weights + wc (126 -> 54 MB traffic).
//   - flash unchanged (proven 49.0us, control).  gemm_wo unchanged.

#define BS 8
#define SEQ 1024
#define DM 512
#define NH 8
#define DK 64
#define ROWS (BS * SEQ)

typedef __bf16 bf16_t;
typedef bf16_t bf16x8 __attribute__((ext_vector_type(8)));
typedef bf16_t bf16x4 __attribute__((ext_vector_type(4)));
typedef float f32x4 __attribute__((ext_vector_type(4)));

__device__ inline f32x4 mfma32(bf16x8 a, bf16x8 b, f32x4 c) {
  return __builtin_amdgcn_mfma_f32_16x16x32_bf16(a, b, c, 0, 0, 0);
}

// async global->LDS, 16 bytes/lane.  LDS dest = wave-uniform base + lane*16.
__device__ inline void gload_lds16(const bf16_t* g, bf16_t* l) {
  __builtin_amdgcn_global_load_lds(
      (const __attribute__((address_space(1))) void*)g,
      (__attribute__((address_space(3))) void*)l, 16, 0, 0);
}

// ---------------------------------------------------------------------------
// prep: {weight fp32->bf16} + {G2 = (1+softmax(wc))*0.125*log2e}.
// blocks [0,128): weights (4 x 32); [128, 128+8192): wc rows.
// ---------------------------------------------------------------------------
__global__ __launch_bounds__(256) void prep_kernel(
    const float* wq, const float* wk, const float* wv, const float* wo,
    bf16_t* wqb, bf16_t* wkb, bf16_t* wvb, bf16_t* wob,
    const float* __restrict__ wc, bf16_t* __restrict__ G) {
  int bx = blockIdx.x;
  int t = threadIdx.x;
  if (bx < 128) {
    const float* srcs[4] = {wq, wk, wv, wo};
    bf16_t* dsts[4] = {wqb, wkb, wvb, wob};
    int seg = bx >> 5, boff = bx & 31;
    const float* src = srcs[seg] + (size_t)boff * 8192;
    bf16_t* dst = dsts[seg] + (size_t)boff * 8192;
#pragma unroll
    for (int f = 0; f < 8; ++f) {
      int idx = (f * 256 + t) * 4;
      float4 x = *(const float4*)(src + idx);
      bf16x4 o;
      o[0] = (bf16_t)x.x; o[1] = (bf16_t)x.y; o[2] = (bf16_t)x.z; o[3] = (bf16_t)x.w;
      *(bf16x4*)(dst + idx) = o;
    }
  } else {
    int row = bx - 128;
    const float* x = wc + (size_t)row * SEQ;
    bf16_t* y = G + (size_t)row * SEQ;
    float4 vv = *(const float4*)(x + t * 4);
    float m = fmaxf(fmaxf(vv.x, vv.y), fmaxf(vv.z, vv.w));
#pragma unroll
    for (int off = 32; off > 0; off >>= 1) m = fmaxf(m, __shfl_xor(m, off, 64));
    __shared__ float sm[4], ss[4];
    int w = t >> 6;
    if ((t & 63) == 0) sm[w] = m;
    __syncthreads();
    m = fmaxf(fmaxf(sm[0], sm[1]), fmaxf(sm[2], sm[3]));
    float4 e;
    e.x = __expf(vv.x - m); e.y = __expf(vv.y - m);
    e.z = __expf(vv.z - m); e.w = __expf(vv.w - m);
    float s = e.x + e.y + e.z + e.w;
#pragma unroll
    for (int off = 32; off > 0; off >>= 1) s += __shfl_xor(s, off, 64);
    if ((t & 63) == 0) ss[w] = s;
    __syncthreads();
    s = ss[0] + ss[1] + ss[2] + ss[3];
    float inv = 1.0f / s;
    const float SC = 0.18033688011112042f;  // 0.125 * log2(e)
    bf16x4 g;
    g[0] = (bf16_t)((1.0f + e.x * inv) * SC);
    g[1] = (bf16_t)((1.0f + e.y * inv) * SC);
    g[2] = (bf16_t)((1.0f + e.z * inv) * SC);
    g[3] = (bf16_t)((1.0f + e.w * inv) * SC);
    *(bf16x4*)(y + t * 4) = g;
  }
}

// ---------------------------------------------------------------------------
// QKV GEMM: C[8192,512] = cast_bf16(X_f32) @ W^T + bias.  BM=128, BN=128,
// BK=32.  A: f32 global -> regs (issued 1 iter early) -> cvt -> ds_write.
// B: global_load_lds.  One barrier/iter.  vtrans epilogue for z==2.
// ---------------------------------------------------------------------------
__device__ inline void gemm_qkv_core(const float* X, const bf16_t* W,
                                     const float* bias, bf16_t* Cv,
                                     int mblk, int nblk, bool vtrans) {
  constexpr int STAGE_B = (2 * 128 * 32 + 2 * 128 * 32) * 2;
  constexpr int EPI_B = 128 * 136 * 2;
  constexpr int SMEM_B = STAGE_B > EPI_B ? STAGE_B : EPI_B;
  __shared__ __align__(16) char smem[SMEM_B];
  bf16_t* As = (bf16_t*)smem;                  // [2][128*32]
  bf16_t* Bs = (bf16_t*)smem + 2 * 128 * 32;   // [2][128*32]

  int t = threadIdx.x, lane = t & 63, w = t >> 6;
  int quad = lane >> 4, l15 = lane & 15;
  int m0w = (w & 1) * 64, n0w = (w >> 1) * 64;
  int mbase = mblk * 128, nbase = nblk * 128;
  int lr = lane >> 2, l4 = lane & 3;
  f32x4 acc[4][4] = {};

  // A reg-staging map: thread t -> row t>>1, half (t&1)*16 floats.
  int arow = t >> 1, ahalf = (t & 1) * 16;
  const float* Xbase = X + (size_t)(mbase + arow) * DM + ahalf;

  float4 arA[4], arB[4];
  auto issueA = [&](int it, float4(&s)[4]) {
    const float* p = Xbase + it * 32;
#pragma unroll
    for (int i = 0; i < 4; ++i) s[i] = *(const float4*)(p + i * 4);
  };
  auto writeA = [&](int buf, float4(&s)[4]) {
    bf16x8 v0, v1;
    v0[0] = (bf16_t)s[0].x; v0[1] = (bf16_t)s[0].y;
    v0[2] = (bf16_t)s[0].z; v0[3] = (bf16_t)s[0].w;
    v0[4] = (bf16_t)s[1].x; v0[5] = (bf16_t)s[1].y;
    v0[6] = (bf16_t)s[1].z; v0[7] = (bf16_t)s[1].w;
    v1[0] = (bf16_t)s[2].x; v1[1] = (bf16_t)s[2].y;
    v1[2] = (bf16_t)s[2].z; v1[3] = (bf16_t)s[2].w;
    v1[4] = (bf16_t)s[3].x; v1[5] = (bf16_t)s[3].y;
    v1[6] = (bf16_t)s[3].z; v1[7] = (bf16_t)s[3].w;
    bf16_t* dst = &As[buf * 4096 + arow * 32 + ahalf];
    *(bf16x8*)dst = v0;
    *(bf16x8*)(dst + 8) = v1;
  };
  auto stageB = [&](int it, int buf) {
#pragma unroll
    for (int f = 0; f < 2; ++f) {
      int i = f * 4 + w;
      gload_lds16(W + (size_t)(nbase + i * 16 + lr) * DM + it * 32 + l4 * 8,
                  &Bs[buf * 4096 + i * 512]);
    }
  };
  auto compute = [&](int cb) {
    bf16x8 af[4], bfr[4];
#pragma unroll
    for (int mt = 0; mt < 4; ++mt)
      af[mt] = *(const bf16x8*)&As[cb * 4096 + (m0w + mt * 16 + l15) * 32 + quad * 8];
#pragma unroll
    for (int nt = 0; nt < 4; ++nt)
      bfr[nt] = *(const bf16x8*)&Bs[cb * 4096 + (n0w + nt * 16 + l15) * 32 + quad * 8];
#pragma unroll
    for (int mt = 0; mt < 4; ++mt)
#pragma unroll
      for (int nt = 0; nt < 4; ++nt)
        acc[mt][nt] = mfma32(af[mt], bfr[nt], acc[mt][nt]);
  };

  // prologue: tile 0 staged (A regs -> LDS, B DMA); tile 1 A-loads in flight
  issueA(0, arA);
  stageB(0, 0);
  issueA(1, arB);
  writeA(0, arA);

#pragma unroll 1
  for (int it2 = 0; it2 < 16; it2 += 2) {
    __syncthreads();  // drains lgkm(A writes) + vmcnt(B DMA) of tile it2
    if (it2 + 1 < 16) {
      stageB(it2 + 1, 1);
      writeA(1, arB);                       // loads issued 1 iter ago
      if (it2 + 2 < 16) issueA(it2 + 2, arA);
    }
    compute(0);
    __syncthreads();
    if (it2 + 2 < 16) {
      stageB(it2 + 2, 0);
      writeA(0, arA);
      if (it2 + 3 < 16) issueA(it2 + 3, arB);
    }
    compute(1);
  }

  if (vtrans) {
    // transposed bf16 tile -> LDS -> coalesced bf16x8 row stores into Vt.
    __syncthreads();
    bf16_t* Ts = (bf16_t*)smem;  // [128 col][136 m]
#pragma unroll
    for (int nt = 0; nt < 4; ++nt) {
      int colL = n0w + nt * 16 + l15;
      float bc = bias[nbase + colL];
#pragma unroll
      for (int mt = 0; mt < 4; ++mt) {
        bf16x4 ov;
#pragma unroll
        for (int r = 0; r < 4; ++r) ov[r] = (bf16_t)(acc[mt][nt][r] + bc);
        *(bf16x4*)&Ts[colL * 136 + m0w + mt * 16 + quad * 4] = ov;
      }
    }
    __syncthreads();
    int b = mbase >> 10;
    int m0 = mbase & 1023;
#pragma unroll
    for (int p = 0; p < 8; ++p) {
      int flat = p * 256 + t;
      int colL = flat >> 4, m8 = (flat & 15) * 8;
      bf16x8 vv = *(const bf16x8*)&Ts[colL * 136 + m8];
      int colG = nbase + colL;
      int hh = colG >> 6, dd = colG & 63;
      *(bf16x8*)&Cv[((size_t)(b * NH + hh) * DK + dd) * SEQ + m0 + m8] = vv;
    }
  } else {
#pragma unroll
    for (int nt = 0; nt < 4; ++nt) {
      int col = nbase + n0w + nt * 16 + l15;
      float bc = bias[col];
#pragma unroll
      for (int mt = 0; mt < 4; ++mt)
#pragma unroll
        for (int r = 0; r < 4; ++r) {
          int row = mbase + m0w + mt * 16 + quad * 4 + r;
          Cv[(size_t)row * DM + col] = (bf16_t)(acc[mt][nt][r] + bc);
        }
    }
  }
}

__global__ __launch_bounds__(256) void gemm_qkv_kernel(
    const float* q, const float* k, const float* v,
    const bf16_t* wq, const bf16_t* wk, const bf16_t* wv,
    const float* bq, const float* bk, const float* bv,
    bf16_t* cq, bf16_t* ck, bf16_t* vt) {
  const float* Xarr[3] = {q, k, v};
  const bf16_t* Warr[3] = {wq, wk, wv};
  const float* barr[3] = {bq, bk, bv};
  bf16_t* Carr[3] = {cq, ck, vt};
  int z = blockIdx.z;
  gemm_qkv_core(Xarr[z], Warr[z], barr[z], Carr[z], blockIdx.x, blockIdx.y, z == 2);
}

// ---------------------------------------------------------------------------
// WO GEMM (unchanged R13): C_f32[8192,512] = Ab_bf16 @ Wo^T + bo.
// BM=64; f32 out staged through LDS -> coalesced float4 stores.
// ---------------------------------------------------------------------------
__global__ __launch_bounds__(256) void gemm_wo_kernel(const bf16_t* X, const bf16_t* W,
                                                      const float* bias, float* C) {
  constexpr int BM = 64;
  constexpr int STAGE_B = (2 * BM * 32 + 2 * 128 * 32) * 2;
  constexpr int EPI_B = BM * 132 * 4;
  constexpr int SMEM_B = STAGE_B > EPI_B ? STAGE_B : EPI_B;
  __shared__ __align__(16) char smem[SMEM_B];
  bf16_t* As = (bf16_t*)smem;
  bf16_t* Bs = (bf16_t*)smem + 2 * BM * 32;
  int mblk = blockIdx.x, nblk = blockIdx.y;

  int t = threadIdx.x, lane = t & 63, w = t >> 6;
  int quad = lane >> 4, l15 = lane & 15;
  constexpr int MT = BM / 32;
  int m0w = (w & 1) * (BM / 2), n0w = (w >> 1) * 64;
  int mbase = mblk * BM, nbase = nblk * 128;
  int lr = lane >> 2, l4 = lane & 3;
  f32x4 acc[MT][4] = {};

#pragma unroll
  for (int f = 0; f < BM / 64; ++f) {
    int i = f * 4 + w;
    gload_lds16(X + (size_t)(mbase + i * 16 + lr) * DM + l4 * 8, &As[i * 512]);
  }
#pragma unroll
  for (int f = 0; f < 2; ++f) {
    int i = f * 4 + w;
    gload_lds16(W + (size_t)(nbase + i * 16 + lr) * DM + l4 * 8, &Bs[i * 512]);
  }

  for (int it = 0; it < 16; ++it) {
    __syncthreads();
    int cb = it & 1;
    if (it + 1 < 16) {
      int kb = (it + 1) * 32, nb = (it + 1) & 1;
#pragma unroll
      for (int f = 0; f < BM / 64; ++f) {
        int i = f * 4 + w;
        gload_lds16(X + (size_t)(mbase + i * 16 + lr) * DM + kb + l4 * 8,
                    &As[nb * BM * 32 + i * 512]);
      }
#pragma unroll
      for (int f = 0; f < 2; ++f) {
        int i = f * 4 + w;
        gload_lds16(W + (size_t)(nbase + i * 16 + lr) * DM + kb + l4 * 8,
                    &Bs[nb * 128 * 32 + i * 512]);
      }
    }
    bf16x8 af[MT], bfr[4];
#pragma unroll
    for (int mt = 0; mt < MT; ++mt)
      af[mt] = *(const bf16x8*)&As[cb * BM * 32 + (m0w + mt * 16 + l15) * 32 + quad * 8];
#pragma unroll
    for (int nt = 0; nt < 4; ++nt)
      bfr[nt] = *(const bf16x8*)&Bs[cb * 128 * 32 + (n0w + nt * 16 + l15) * 32 + quad * 8];
#pragma unroll
    for (int mt = 0; mt < MT; ++mt)
#pragma unroll
      for (int nt = 0; nt < 4; ++nt)
        acc[mt][nt] = mfma32(af[mt], bfr[nt], acc[mt][nt]);
  }

  __syncthreads();
  float* Cs = (float*)smem;  // [BM][132]
#pragma unroll
  for (int nt = 0; nt < 4; ++nt) {
    int colL = n0w + nt * 16 + l15;
    float bc = bias[nbase + colL];
#pragma unroll
    for (int mt = 0; mt < MT; ++mt)
#pragma unroll
      for (int r = 0; r < 4; ++r)
        Cs[(m0w + mt * 16 + quad * 4 + r) * 132 + colL] = acc[mt][nt][r] + bc;
  }
  __syncthreads();
  constexpr int NP = BM * 128 / 4 / 256;
#pragma unroll
  for (int p = 0; p < NP; ++p) {
    int flat = p * 256 + t;
    int row = flat >> 5, c4 = (flat & 31) * 4;
    float4 vv = *(const float4*)&Cs[row * 132 + c4];
    *(float4*)&C[(size_t)(mbase + row) * DM + nbase + c4] = vv;
  }
}

// ---------------------------------------------------------------------------
// Flash attention (R12/R13, unchanged -- proven 49.0us).
// ---------------------------------------------------------------------------
__global__ __launch_bounds__(256, 4) void flash_mfma_kernel(
    const bf16_t* __restrict__ Qb, const bf16_t* __restrict__ Kb,
    const bf16_t* __restrict__ Vt, const bf16_t* __restrict__ G,
    bf16_t* __restrict__ Ab) {
  int flat = blockIdx.x + 16 * (blockIdx.y + 8 * blockIdx.z);
  int l = (flat & 7) * 128 + (flat >> 3);
  int qt = l & 15, h = (l >> 4) & 7, b = l >> 7;

  __shared__ bf16_t Ks[2][64 * 64];
  __shared__ bf16_t Vs[2][64 * 64];
  __shared__ bf16_t Ps[4][16 * 64];
  int t = threadIdx.x, lane = t & 63, w = t >> 6;
  int quad = lane >> 4, l15 = lane & 15;
  int k7 = l15 & 7;

  int srow[2], scol[2];
#pragma unroll
  for (int f = 0; f < 2; ++f) {
    int idx = f * 256 + t;
    int r = idx >> 3, p = idx & 7;
    srow[f] = r;
    scol[f] = ((p ^ (r & 7)) * 8);
  }
  const bf16_t* Kbase = Kb + (size_t)(b * SEQ) * DM + h * DK;
  const bf16_t* Vbase = Vt + (size_t)((b * NH + h) * DK) * SEQ;

  size_t qrow_g = (size_t)(b * SEQ + qt * 64 + w * 16 + l15) * DM + h * DK;
  bf16x8 aq0 = *(const bf16x8*)&Qb[qrow_g + quad * 8];
  bf16x8 aq1 = *(const bf16x8*)&Qb[qrow_g + 32 + quad * 8];

  const size_t grow = (size_t)(b * SEQ + qt * 64 + w * 16 + l15) * SEQ;
  bf16x4 greg[4];
#pragma unroll
  for (int ct = 0; ct < 4; ++ct)
    greg[ct] = *(const bf16x4*)&G[grow + ct * 16 + quad * 4];

#pragma unroll
  for (int f = 0; f < 2; ++f) {
    int cbase = (f * 256 + w * 64) * 8;
    gload_lds16(Kbase + (size_t)srow[f] * DM + scol[f], &Ks[0][cbase]);
    gload_lds16(Vbase + (size_t)srow[f] * SEQ + scol[f], &Vs[0][cbase]);
  }
  asm volatile("s_waitcnt vmcnt(0)" ::: "memory");
  asm volatile("s_barrier" ::: "memory");

  float l_st = 0.f;
  f32x4 o[4] = {};

  for (int mt = 0; mt < 16; ++mt) {
    int cb = mt & 1;
    if (mt < 15) {
      int nb = cb ^ 1;
      const bf16_t* Kn = Kbase + (size_t)(mt + 1) * 64 * DM;
      const bf16_t* Vn = Vbase + (mt + 1) * 64;
#pragma unroll
      for (int f = 0; f < 2; ++f) {
        int cbase = (f * 256 + w * 64) * 8;
        gload_lds16(Kn + (size_t)srow[f] * DM + scol[f], &Ks[nb][cbase]);
        gload_lds16(Vn + (size_t)srow[f] * SEQ + scol[f], &Vs[nb][cbase]);
      }
      asm volatile("" ::: "memory");
    }

    f32x4 s[4];
    __builtin_amdgcn_s_setprio(1);
#pragma unroll
    for (int ct = 0; ct < 4; ++ct) {
      int r = ct * 16 + l15;
      int sw = r & 7;
      bf16x8 ak0 = *(const bf16x8*)&Ks[cb][r * 64 + ((quad ^ sw) * 8)];
      bf16x8 ak1 = *(const bf16x8*)&Ks[cb][r * 64 + (((4 + quad) ^ sw) * 8)];
      f32x4 z = {};
      s[ct] = mfma32(ak1, aq1, mfma32(ak0, aq0, z));
    }
    __builtin_amdgcn_s_setprio(0);

    float rs = 0.f;
#pragma unroll
    for (int ct = 0; ct < 4; ++ct) {
      bf16x4 pb;
#pragma unroll
      for (int r = 0; r < 4; ++r) {
        float p = __builtin_amdgcn_exp2f(s[ct][r] * (float)greg[ct][r]);
        pb[r] = (bf16_t)p;
        rs += p;
      }
      int chunk = (2 * ct + (quad >> 1)) ^ k7;
      *(bf16x4*)&Ps[w][l15 * 64 + chunk * 8 + (quad & 1) * 4] = pb;
    }
    if (mt < 15) {
#pragma unroll
      for (int ct = 0; ct < 4; ++ct)
        greg[ct] = *(const bf16x4*)&G[grow + (mt + 1) * 64 + ct * 16 + quad * 4];
    }
    rs += __shfl_xor(rs, 16, 64);
    rs += __shfl_xor(rs, 32, 64);
    l_st += rs;

    __builtin_amdgcn_s_setprio(1);
#pragma unroll
    for (int c = 0; c < 2; ++c) {
      int pchunk = (4 * c + quad) ^ k7;
      bf16x8 bp = *(const bf16x8*)&Ps[w][l15 * 64 + pchunk * 8];
#pragma unroll
      for (int dt = 0; dt < 4; ++dt) {
        int d = dt * 16 + l15;
        int vchunk = (4 * c + quad) ^ (d & 7);
        bf16x8 av = *(const bf16x8*)&Vs[cb][d * 64 + vchunk * 8];
        o[dt] = mfma32(av, bp, o[dt]);
      }
    }
    __builtin_amdgcn_s_setprio(0);

    if (mt < 15) {
      asm volatile("s_waitcnt vmcnt(4)" ::: "memory");
      asm volatile("s_barrier" ::: "memory");
    }
  }

  float linv = 1.0f / l_st;
#pragma unroll
  for (int dt = 0; dt < 4; ++dt) {
    bf16x4 ov;
#pragma unroll
    for (int r = 0; r < 4; ++r) ov[r] = (bf16_t)(o[dt][r] * linv);
    *(bf16x4*)&Ab[qrow_g + dt * 16 + quad * 4] = ov;
  }
}

// ---------------------------------------------------------------------------
extern "C" void kernel_launch(void* const* d_in, const int* in_sizes, int n_in,
                              void* d_out, int out_size, void* d_ws, size_t ws_size,
                              hipStream_t stream) {
  const float* query = (const float*)d_in[0];
  const float* key = (const float*)d_in[1];
  const float* value = (const float*)d_in[2];
  const float* wc = (const float*)d_in[3];
  const float* Wq = (const float*)d_in[4];
  const float* bq = (const float*)d_in[5];
  const float* Wk = (const float*)d_in[6];
  const float* bk = (const float*)d_in[7];
  const float* Wv = (const float*)d_in[8];
  const float* bv = (const float*)d_in[9];
  const float* Wo = (const float*)d_in[10];
  const float* bo = (const float*)d_in[11];
  float* out = (float*)d_out;

  const size_t ACT = (size_t)ROWS * DM;
  const size_t WSZ = (size_t)DM * DM;
  bf16_t* Qb = (bf16_t*)d_ws;
  bf16_t* Kb = Qb + ACT;
  bf16_t* Vb = Kb + ACT;  // unused (layout stability)
  bf16_t* Vt = Vb + ACT;
  bf16_t* Ab = Vt + ACT;
  bf16_t* G = Ab + ACT;
  bf16_t* Wqb = G + (size_t)BS * SEQ * SEQ;
  bf16_t* Wkb = Wqb + WSZ;
  bf16_t* Wvb = Wkb + WSZ;
  bf16_t* Wob = Wvb + WSZ;

  prep_kernel<<<128 + BS * SEQ, 256, 0, stream>>>(
      Wq, Wk, Wv, Wo, Wqb, Wkb, Wvb, Wob, wc, G);

  gemm_qkv_kernel<<<dim3(ROWS / 128, DM / 128, 3), 256, 0, stream>>>(
      query, key, value, Wqb, Wkb, Wvb, bq, bk, bv, Qb, Kb, Vt);

  flash_mfma_kernel<<<dim3(SEQ / 64, NH, BS), 256, 0, stream>>>(Qb, Kb, Vt, G, Ab);

  gemm_wo_kernel<<<dim3(ROWS / 64, DM / 128), 256, 0, stream>>>(Ab, Wob, bo, out);
}